// Round 11
// baseline (107.713 us; speedup 1.0000x reference)
//
#include <hip/hip_runtime.h>

typedef __bf16 bf16x8 __attribute__((ext_vector_type(8)));
typedef float f32x4 __attribute__((ext_vector_type(4)));

#define TWO_LOG2E 2.88539008177792681f   // 2*log2(e): exp(2x) = exp2(x*TWO_LOG2E)

#define GLOADLDS16(g, l) __builtin_amdgcn_global_load_lds(                     \
    (const __attribute__((address_space(1))) void*)(g),                        \
    (__attribute__((address_space(3))) void*)(l), 16, 0, 0)

__device__ __forceinline__ unsigned f2bf(float f) {
    unsigned u = __float_as_uint(f);
    return (u + 0x7FFFu + ((u >> 16) & 1u)) >> 16;   // RNE
}

// ---------------- kernel 1: row-normalize z=[z1;z2] -> bf16 zn[8192][256] ---------------
__global__ void __launch_bounds__(256) normalize_kernel(
    const float* __restrict__ z1, const float* __restrict__ z2,
    unsigned short* __restrict__ zn, float* __restrict__ S, float* __restrict__ out)
{
    if (blockIdx.x < 32) S[(blockIdx.x << 8) + threadIdx.x] = 0.f;
    if (blockIdx.x == 32 && threadIdx.x == 0) out[0] = 0.f;

    const int wave = threadIdx.x >> 6, lane = threadIdx.x & 63;
    const int row = (blockIdx.x << 2) + wave;               // 2048 blocks * 4 rows
    const float* src = (row < 4096) ? (z1 + row * 256) : (z2 + (row - 4096) * 256);
    float4 v = ((const float4*)src)[lane];                  // 64 lanes * 4 = 256
    float ss = v.x * v.x + v.y * v.y + v.z * v.z + v.w * v.w;
#pragma unroll
    for (int m = 32; m > 0; m >>= 1) ss += __shfl_xor(ss, m, 64);
    float sc = 1.0f / fmaxf(sqrtf(ss), 1e-8f);
    uint2 w;
    w.x = f2bf(v.x * sc) | (f2bf(v.y * sc) << 16);
    w.y = f2bf(v.z * sc) | (f2bf(v.w * sc) << 16);
    *(uint2*)(zn + row * 256 + (lane << 2)) = w;
}

// ---------------- kernel 2: triangle, 4-wave blocks, 64 rows/wave (fat waves) ----------
// Invariant across R0/R1/R4/R8/R9: simexp ~40us while traffic/work/occupancy all varied
// -> barrier-every-interval convoys all waves through the same phase; pipes don't
// overlap. R10 halves per-CU instruction pressure at constant MFMA work: each wave owns
// 64 rows (a[4][8] = 128 VGPRs, 16 MFMA per chunk vs 8), blocks are 4 waves / 256 thr,
// tile stays 256x256. Per-chunk per-wave cost flips from LDS-bound (8 MFMA=39cy vs
// 4 ds_read=48cy) to MFMA-bound (16 MFMA=78cy). __launch_bounds__(256,2) -> 256-VGPR
// cap, need ~210: real headroom (R5's spill was 190-need vs 128-cap; do NOT tighten).
// Staging/sync = R1-proven form verbatim: every wave stages one 16B-slot quarter
// (s=(wv<<6)+lane, 128B-contiguous rows, XOR swizzle), ring-4 depth-2, counted
// `s_waitcnt vmcnt(2)` steady / 1 / 0 drain, raw s_barrier publish. NEVER __syncthreads
// mid-loop. Off-diag: rows->rs atomic flush + colpart LDS cross-wave reduce (ONE
// atomic/col). Diag: row path only (full tile covers both orderings; finish subtracts
// self-sim). Decode = R8's scan (R9's XCD map: no effect, reverted).
__global__ void __launch_bounds__(256, 2) simexp_kernel(
    const unsigned short* __restrict__ zn, float* __restrict__ S)
{
    __shared__ __align__(16) unsigned short Bs[4][2048];    // 4 x 4KB ring
    __shared__ float colpart[4][256];                       // per-wave col partials

    const int tid = threadIdx.x;
    const int wv = tid >> 6, lane = tid & 63;
    const int q = lane >> 4, n16 = lane & 15;
    const int job = blockIdx.x;                 // 0..527

    int ti, tj;
    bool diag;
    if (job >= 496) {                           // diagonal tile
        ti = tj = job - 496;
        diag = true;
    } else {                                    // off-diag tile, ti<tj
        int t = 0, rem = job;
        while (rem >= 31 - t) { rem -= 31 - t; ++t; }   // uniform scan, <=31 iters
        ti = t; tj = t + 1 + rem;
        diag = false;
    }
    const int colTile = tj << 8;
    const int rowW = (ti << 8) + (wv << 6);     // this wave's 64 rows

    // A: 64 rows x K=256 in registers (frag: row=n16, k=q*8 within 32-elem step)
    bf16x8 a[4][8];
#pragma unroll
    for (int rt = 0; rt < 4; ++rt)
#pragma unroll
        for (int ks = 0; ks < 8; ++ks)
            a[rt][ks] = *(const bf16x8*)(zn + ((rowW + (rt << 4) + n16) << 8)
                                            + (ks << 5) + (q << 3));

    auto stage = [&](int m) {                   // every wave stages its quarter (R1 form)
        const int colBase = colTile + ((m >> 2) << 5);
        const int koff = (m & 3) << 6;
        unsigned short* base = &Bs[m & 3][0];
        int s = (wv << 6) + lane;               // 16B slot 0..255
        int c = s >> 3, d = s & 7;              // 8 consecutive lanes per row -> 128B
        int k8 = d ^ (c & 7);                   // XOR swizzle (conflict-free b128 reads)
        GLOADLDS16(zn + ((colBase + c) << 8) + koff + (k8 << 3), base + (s << 3));
    };

    float rs[4][4];
#pragma unroll
    for (int i = 0; i < 4; ++i)
#pragma unroll
        for (int j = 0; j < 4; ++j) rs[i][j] = 0.f;

    f32x4 acc[4][2];
    auto consume = [&](int kc) {                // buffer kc (m&3==kc since m=cc*4+kc)
        const unsigned short* bb = &Bs[kc & 3][0];
#pragma unroll
        for (int ks = 0; ks < 2; ++ks) {
            bf16x8 bf[2];
#pragma unroll
            for (int ct = 0; ct < 2; ++ct) {
                int c  = (ct << 4) + n16;               // col 0..31
                int k8 = ((ks << 2) + q) ^ (c & 7);     // swizzled chunk
                bf[ct] = *(const bf16x8*)(bb + (((c << 3) + k8) << 3));
            }
#pragma unroll
            for (int rt = 0; rt < 4; ++rt)
#pragma unroll
                for (int ct = 0; ct < 2; ++ct)
                    acc[rt][ct] = __builtin_amdgcn_mfma_f32_16x16x32_bf16(
                        a[rt][(kc << 1) + ks], bf[ct], acc[rt][ct], 0, 0, 0);
        }
    };
    auto zacc = [&]() {
#pragma unroll
        for (int rt = 0; rt < 4; ++rt)
#pragma unroll
            for (int ct = 0; ct < 2; ++ct) acc[rt][ct] = (f32x4){0.f, 0.f, 0.f, 0.f};
    };
    auto epiC = [&](int cc) {                   // rows -> rs; cols -> colpart (off-diag)
        float cs[2] = {0.f, 0.f};
#pragma unroll
        for (int rt = 0; rt < 4; ++rt)
#pragma unroll
            for (int ct = 0; ct < 2; ++ct)
#pragma unroll
                for (int r = 0; r < 4; ++r) {
                    float e = __builtin_amdgcn_exp2f(acc[rt][ct][r] * TWO_LOG2E);
                    rs[rt][r] += e;
                    cs[ct] += e;
                }
        if (!diag) {                            // wave-uniform
#pragma unroll
            for (int ct = 0; ct < 2; ++ct) {
                float s = cs[ct];
                s += __shfl_xor(s, 16, 64);     // reduce over q
                s += __shfl_xor(s, 32, 64);
                if (lane < 16) colpart[wv][(cc << 5) + (ct << 4) + n16] = s;
            }
        }
    };

    stage(0);                                   // prologue: depth-2
    stage(1);

    for (int cc = 0; cc < 7; ++cc) {            // intervals m=cc*4+kc, m=0..27
        zacc();
#pragma unroll
        for (int kc = 0; kc < 4; ++kc) {
            stage((cc << 2) + kc + 2);
            asm volatile("s_waitcnt vmcnt(2)" ::: "memory");  // own chunk-m loads done
            __builtin_amdgcn_s_barrier();
            asm volatile("" ::: "memory");      // keep ds_reads below the barrier
            consume(kc);
        }
        epiC(cc);
    }
    // peeled tail cc=7: chunks 28..31 (stage 30, 31 then drain 2->1->0)
    zacc();
    stage(30);
    asm volatile("s_waitcnt vmcnt(2)" ::: "memory");
    __builtin_amdgcn_s_barrier();
    asm volatile("" ::: "memory");
    consume(0);
    stage(31);
    asm volatile("s_waitcnt vmcnt(2)" ::: "memory");
    __builtin_amdgcn_s_barrier();
    asm volatile("" ::: "memory");
    consume(1);
    asm volatile("s_waitcnt vmcnt(1)" ::: "memory");
    __builtin_amdgcn_s_barrier();
    asm volatile("" ::: "memory");
    consume(2);
    asm volatile("s_waitcnt vmcnt(0)" ::: "memory");
    __builtin_amdgcn_s_barrier();
    asm volatile("" ::: "memory");
    consume(3);
    epiC(7);

    // row flush (C/D layout: col=n16, row=q*4+r); wave covers 64 rows
#pragma unroll
    for (int rt = 0; rt < 4; ++rt)
#pragma unroll
        for (int r = 0; r < 4; ++r) {
            float s = rs[rt][r];
            s += __shfl_xor(s, 1, 64);
            s += __shfl_xor(s, 2, 64);
            s += __shfl_xor(s, 4, 64);
            s += __shfl_xor(s, 8, 64);
            if (n16 == 0) atomicAdd(&S[rowW + (rt << 4) + (q << 2) + r], s);
        }

    // off-diag only: cross-wave col reduction, ONE atomic per column. vmcnt fully
    // drained above -> __syncthreads is safe here (publishes colpart writes).
    if (!diag) {
        __syncthreads();
        {
            float s = 0.f;
#pragma unroll
            for (int w = 0; w < 4; ++w) s += colpart[w][tid];
            atomicAdd(&S[colTile + tid], s);
        }
    }
}

// ---------------- kernel 3: loss = mean( log(S_i - e^{sim_ii}) - sim_{i,target} ) -------
__global__ void __launch_bounds__(256) finish_kernel(
    const unsigned short* __restrict__ zn, const float* __restrict__ S,
    float* __restrict__ out)
{
    __shared__ float vals[16];
    const int tid = threadIdx.x, lane = tid & 63, wave = tid >> 6;
    const int q = lane >> 4, n16 = lane & 15;
    const int rib = (wave << 2) + q;                // 0..15 rows per block
    const int row = (blockIdx.x << 4) + rib;        // 512 blocks * 16 rows
    const int tar = (row + 4096) & 8191;

    float drr = 0.f, drt = 0.f;
#pragma unroll
    for (int i = 0; i < 4; ++i) {
        int k = (i << 6) + (n16 << 2);
        uint2 ur = *(const uint2*)(zn + (row << 8) + k);
        uint2 ut = *(const uint2*)(zn + (tar << 8) + k);
        float a0 = __uint_as_float(ur.x << 16),  a1 = __uint_as_float(ur.x & 0xFFFF0000u);
        float a2 = __uint_as_float(ur.y << 16),  a3 = __uint_as_float(ur.y & 0xFFFF0000u);
        float b0 = __uint_as_float(ut.x << 16),  b1 = __uint_as_float(ut.x & 0xFFFF0000u);
        float b2 = __uint_as_float(ut.y << 16),  b3 = __uint_as_float(ut.y & 0xFFFF0000u);
        drr += a0 * a0 + a1 * a1 + a2 * a2 + a3 * a3;
        drt += a0 * b0 + a1 * b1 + a2 * b2 + a3 * b3;
    }
#pragma unroll
    for (int m = 1; m <= 8; m <<= 1) {
        drr += __shfl_xor(drr, m, 64);
        drt += __shfl_xor(drt, m, 64);
    }
    if (n16 == 0) {
        float Sv = S[row] - __builtin_amdgcn_exp2f(drr * TWO_LOG2E);  // remove diagonal
        vals[rib] = 0.693147180559945f * __builtin_amdgcn_logf(Sv) - 2.0f * drt;
    }
    __syncthreads();
    if (tid == 0) {
        float s = 0.f;
#pragma unroll
        for (int i = 0; i < 16; ++i) s += vals[i];
        atomicAdd(out, s * (1.0f / 8192.0f));
    }
}

extern "C" void kernel_launch(void* const* d_in, const int* in_sizes, int n_in,
                              void* d_out, int out_size, void* d_ws, size_t ws_size,
                              hipStream_t stream)
{
    const float* z1 = (const float*)d_in[0];
    const float* z2 = (const float*)d_in[1];
    unsigned short* zn = (unsigned short*)d_ws;                              // 4 MB
    float* S = (float*)((char*)d_ws + 8192 * 256 * sizeof(unsigned short));  // 32 KB
    float* out = (float*)d_out;

    normalize_kernel<<<2048, 256, 0, stream>>>(z1, z2, zn, S, out);
    simexp_kernel<<<528, 256, 0, stream>>>(zn, S);
    finish_kernel<<<512, 256, 0, stream>>>(zn, S, out);
}

// Round 12
// 101.303 us; speedup vs baseline: 1.0633x; 1.0633x over previous
//
#include <hip/hip_runtime.h>

typedef __bf16 bf16x8 __attribute__((ext_vector_type(8)));
typedef float f32x4 __attribute__((ext_vector_type(4)));

#define TWO_LOG2E 2.88539008177792681f   // 2*log2(e): exp(2x) = exp2(x*TWO_LOG2E)

#define GLOADLDS16(g, l) __builtin_amdgcn_global_load_lds(                     \
    (const __attribute__((address_space(1))) void*)(g),                        \
    (__attribute__((address_space(3))) void*)(l), 16, 0, 0)

__device__ __forceinline__ unsigned f2bf(float f) {
    unsigned u = __float_as_uint(f);
    return (u + 0x7FFFu + ((u >> 16) & 1u)) >> 16;   // RNE
}

// ---------------- kernel 1: row-normalize z=[z1;z2] -> bf16 zn[8192][256] ---------------
__global__ void __launch_bounds__(256) normalize_kernel(
    const float* __restrict__ z1, const float* __restrict__ z2,
    unsigned short* __restrict__ zn, float* __restrict__ S, float* __restrict__ out)
{
    if (blockIdx.x < 32) S[(blockIdx.x << 8) + threadIdx.x] = 0.f;
    if (blockIdx.x == 32 && threadIdx.x == 0) out[0] = 0.f;

    const int wave = threadIdx.x >> 6, lane = threadIdx.x & 63;
    const int row = (blockIdx.x << 2) + wave;               // 2048 blocks * 4 rows
    const float* src = (row < 4096) ? (z1 + row * 256) : (z2 + (row - 4096) * 256);
    float4 v = ((const float4*)src)[lane];                  // 64 lanes * 4 = 256
    float ss = v.x * v.x + v.y * v.y + v.z * v.z + v.w * v.w;
#pragma unroll
    for (int m = 32; m > 0; m >>= 1) ss += __shfl_xor(ss, m, 64);
    float sc = 1.0f / fmaxf(sqrtf(ss), 1e-8f);
    uint2 w;
    w.x = f2bf(v.x * sc) | (f2bf(v.y * sc) << 16);
    w.y = f2bf(v.z * sc) | (f2bf(v.w * sc) << 16);
    *(uint2*)(zn + row * 256 + (lane << 2)) = w;
}

// ---------------- kernel 2: R8 skeleton, 8KB chunks -> HALF the sync points ------------
// Surviving hypothesis after R0-R11 (traffic, locality, occupancy, instr-pressure all
// falsified at constant ~40us): cost is per-SYNC-POINT (vmcnt+barrier+ds-latency chain
// ~2360cy per interval vs ~400cy work). R12 halves sync points at fixed everything
// else: chunk = 32 cols x 128 k (8KB, was 4KB), 16 intervals/tile (was 32), per
// interval 2x work (8 ds_read_b128 + 16 MFMA per wave; still ONE global_load_lds per
// wave: 512 slots = 512 threads). Ring-4 = 32KB LDS (+8KB colpart = 40KB; 2 blocks/CU
// = 80KB). Depth-2 prefetch, counted vmcnt(2), drain 1->0 in the 2-interval tail.
// Swizzle generalizes d^(c&7) -> d^(c&15) (16 slots/col; 2-way bank alias = free).
// Everything else = R8 verbatim (triangle decode, diag row-only, colpart reduction).
// Spill tripwire: WRITE_SIZE > 15MB means VGPR cap 128 blown (R5 signature).
__global__ void __launch_bounds__(512, 4) simexp_kernel(
    const unsigned short* __restrict__ zn, float* __restrict__ S)
{
    __shared__ __align__(16) unsigned short Bs[4][4096];    // 4 x 8KB ring
    __shared__ float colpart[8][256];                       // per-wave col partials

    const int tid = threadIdx.x;
    const int wv = tid >> 6, lane = tid & 63;
    const int q = lane >> 4, n16 = lane & 15;
    const int job = blockIdx.x;                 // 0..527

    int ti, tj;
    bool diag;
    if (job >= 496) {                           // diagonal tile
        ti = tj = job - 496;
        diag = true;
    } else {                                    // off-diag tile, ti<tj
        int t = 0, rem = job;
        while (rem >= 31 - t) { rem -= 31 - t; ++t; }   // uniform scan, <=31 iters
        ti = t; tj = t + 1 + rem;
        diag = false;
    }
    const int colTile = tj << 8;
    const int rowW = (ti << 8) + (wv << 5);     // this wave's 32 rows

    // A: 32 rows x K=256 in registers (frag: row=n16, k = f*32 + q*8)
    bf16x8 a[2][8];
#pragma unroll
    for (int rt = 0; rt < 2; ++rt)
#pragma unroll
        for (int f = 0; f < 8; ++f)
            a[rt][f] = *(const bf16x8*)(zn + ((rowW + (rt << 4) + n16) << 8)
                                           + (f << 5) + (q << 3));

    // stage chunk m (col-chunk m>>1, k-half m&1): 512 slots, one 16B slot per thread.
    // 16 consecutive lanes cover one col's 256B (permuted 16B slots) -> coalesced.
    auto stage = [&](int m) {
        const int colBase = colTile + ((m >> 1) << 5);
        const int koff = (m & 1) << 7;          // 0 or 128 elements
        unsigned short* base = &Bs[m & 3][0];
        int s = (wv << 6) + lane;               // slot 0..511
        int c = s >> 4, d = s & 15;             // col 0..31, 16B slot 0..15 within col
        int k8 = d ^ (c & 15);                  // XOR swizzle (conflict-free b128 reads)
        GLOADLDS16(zn + ((colBase + c) << 8) + koff + (k8 << 3), base + (s << 3));
    };

    float rs[2][4];
#pragma unroll
    for (int i = 0; i < 2; ++i)
#pragma unroll
        for (int j = 0; j < 4; ++j) rs[i][j] = 0.f;

    f32x4 acc[2][2];
    // consume chunk in buffer `buf` for k-half h (h compile-time via unroll)
    auto consume = [&](int buf, int h) {
        const unsigned short* bb = &Bs[buf][0];
#pragma unroll
        for (int ks = 0; ks < 4; ++ks) {
            bf16x8 bf[2];
#pragma unroll
            for (int ct = 0; ct < 2; ++ct) {
                int c  = (ct << 4) + n16;               // col 0..31
                int k8 = (ks << 2) + q;                 // 16B slot 0..15
                bf[ct] = *(const bf16x8*)(bb + (((c << 4) + (k8 ^ (c & 15))) << 3));
            }
#pragma unroll
            for (int rt = 0; rt < 2; ++rt)
#pragma unroll
                for (int ct = 0; ct < 2; ++ct)
                    acc[rt][ct] = __builtin_amdgcn_mfma_f32_16x16x32_bf16(
                        a[rt][(h << 2) + ks], bf[ct], acc[rt][ct], 0, 0, 0);
        }
    };
    auto zacc = [&]() {
#pragma unroll
        for (int rt = 0; rt < 2; ++rt)
#pragma unroll
            for (int ct = 0; ct < 2; ++ct) acc[rt][ct] = (f32x4){0.f, 0.f, 0.f, 0.f};
    };
    auto epiC = [&](int cc) {                   // rows -> rs; cols -> colpart (off-diag)
        float cs[2] = {0.f, 0.f};
#pragma unroll
        for (int rt = 0; rt < 2; ++rt)
#pragma unroll
            for (int ct = 0; ct < 2; ++ct)
#pragma unroll
                for (int r = 0; r < 4; ++r) {
                    float e = __builtin_amdgcn_exp2f(acc[rt][ct][r] * TWO_LOG2E);
                    rs[rt][r] += e;
                    cs[ct] += e;
                }
        if (!diag) {                            // wave-uniform
#pragma unroll
            for (int ct = 0; ct < 2; ++ct) {
                float s = cs[ct];
                s += __shfl_xor(s, 16, 64);     // reduce over q
                s += __shfl_xor(s, 32, 64);
                if (lane < 16) colpart[wv][(cc << 5) + (ct << 4) + n16] = s;
            }
        }
    };

    stage(0);                                   // prologue: depth-2
    stage(1);

    for (int cc = 0; cc < 7; ++cc) {            // intervals m = cc*2+h, m = 0..13
        zacc();
#pragma unroll
        for (int h = 0; h < 2; ++h) {
            const int m = (cc << 1) + h;
            stage(m + 2);                       // stages chunks 2..15
            asm volatile("s_waitcnt vmcnt(2)" ::: "memory");  // chunk-m load done
            __builtin_amdgcn_s_barrier();
            asm volatile("" ::: "memory");      // keep ds_reads below the barrier
            consume(m & 3, h);
        }
        epiC(cc);
    }
    // peeled tail cc=7: intervals 14,15 (no stages left; drain 1->0)
    zacc();
    asm volatile("s_waitcnt vmcnt(1)" ::: "memory");
    __builtin_amdgcn_s_barrier();
    asm volatile("" ::: "memory");
    consume(2, 0);                              // m=14, buf 2
    asm volatile("s_waitcnt vmcnt(0)" ::: "memory");
    __builtin_amdgcn_s_barrier();
    asm volatile("" ::: "memory");
    consume(3, 1);                              // m=15, buf 3
    epiC(7);

    // row flush (C/D layout: col=n16, row=q*4+r)
#pragma unroll
    for (int rt = 0; rt < 2; ++rt)
#pragma unroll
        for (int r = 0; r < 4; ++r) {
            float s = rs[rt][r];
            s += __shfl_xor(s, 1, 64);
            s += __shfl_xor(s, 2, 64);
            s += __shfl_xor(s, 4, 64);
            s += __shfl_xor(s, 8, 64);
            if (n16 == 0) atomicAdd(&S[rowW + (rt << 4) + (q << 2) + r], s);
        }

    // off-diag only: cross-wave col reduction, ONE atomic per column. vmcnt fully
    // drained above -> __syncthreads is safe here (publishes colpart writes).
    if (!diag) {
        __syncthreads();
        if (tid < 256) {
            float s = 0.f;
#pragma unroll
            for (int w = 0; w < 8; ++w) s += colpart[w][tid];
            atomicAdd(&S[colTile + tid], s);
        }
    }
}

// ---------------- kernel 3: loss = mean( log(S_i - e^{sim_ii}) - sim_{i,target} ) -------
__global__ void __launch_bounds__(256) finish_kernel(
    const unsigned short* __restrict__ zn, const float* __restrict__ S,
    float* __restrict__ out)
{
    __shared__ float vals[16];
    const int tid = threadIdx.x, lane = tid & 63, wave = tid >> 6;
    const int q = lane >> 4, n16 = lane & 15;
    const int rib = (wave << 2) + q;                // 0..15 rows per block
    const int row = (blockIdx.x << 4) + rib;        // 512 blocks * 16 rows
    const int tar = (row + 4096) & 8191;

    float drr = 0.f, drt = 0.f;
#pragma unroll
    for (int i = 0; i < 4; ++i) {
        int k = (i << 6) + (n16 << 2);
        uint2 ur = *(const uint2*)(zn + (row << 8) + k);
        uint2 ut = *(const uint2*)(zn + (tar << 8) + k);
        float a0 = __uint_as_float(ur.x << 16),  a1 = __uint_as_float(ur.x & 0xFFFF0000u);
        float a2 = __uint_as_float(ur.y << 16),  a3 = __uint_as_float(ur.y & 0xFFFF0000u);
        float b0 = __uint_as_float(ut.x << 16),  b1 = __uint_as_float(ut.x & 0xFFFF0000u);
        float b2 = __uint_as_float(ut.y << 16),  b3 = __uint_as_float(ut.y & 0xFFFF0000u);
        drr += a0 * a0 + a1 * a1 + a2 * a2 + a3 * a3;
        drt += a0 * b0 + a1 * b1 + a2 * b2 + a3 * b3;
    }
#pragma unroll
    for (int m = 1; m <= 8; m <<= 1) {
        drr += __shfl_xor(drr, m, 64);
        drt += __shfl_xor(drt, m, 64);
    }
    if (n16 == 0) {
        float Sv = S[row] - __builtin_amdgcn_exp2f(drr * TWO_LOG2E);  // remove diagonal
        vals[rib] = 0.693147180559945f * __builtin_amdgcn_logf(Sv) - 2.0f * drt;
    }
    __syncthreads();
    if (tid == 0) {
        float s = 0.f;
#pragma unroll
        for (int i = 0; i < 16; ++i) s += vals[i];
        atomicAdd(out, s * (1.0f / 8192.0f));
    }
}

extern "C" void kernel_launch(void* const* d_in, const int* in_sizes, int n_in,
                              void* d_out, int out_size, void* d_ws, size_t ws_size,
                              hipStream_t stream)
{
    const float* z1 = (const float*)d_in[0];
    const float* z2 = (const float*)d_in[1];
    unsigned short* zn = (unsigned short*)d_ws;                              // 4 MB
    float* S = (float*)((char*)d_ws + 8192 * 256 * sizeof(unsigned short));  // 32 KB
    float* out = (float*)d_out;

    normalize_kernel<<<2048, 256, 0, stream>>>(z1, z2, zn, S, out);
    simexp_kernel<<<528, 512, 0, stream>>>(zn, S);
    finish_kernel<<<512, 256, 0, stream>>>(zn, S, out);
}